// Round 1
// baseline (208.517 us; speedup 1.0000x reference)
//
#include <hip/hip_runtime.h>

// SubjectConditionalLinear: y[b,n,o] = sum_h x[b,n,h] * W[sid[b],o,h] + bias[sid[b],o]
// x: [32,512,1024] f32, subject_id: [32] i32, weight: [8,1024,1024] f32, bias: [8,1024] f32
// out: [32,512,1024] f32
//
// Strategy: per-batch bf16 MFMA GEMM (threshold is bf16-scaled; fp32 accum).
// 128x128 tile, BK=64, 4 waves (2x2), wave = 64x64 = 4x4 of 16x16x32 mfma.
// fp32 global -> reg -> cvt_pk bf16 -> LDS (padded rows), ds_read_b128 frags.

constexpr int S_DIM = 8;
constexpr int O_DIM = 1024;
constexpr int H_DIM = 1024;
constexpr int B_DIM = 32;
constexpr int N_DIM = 512;

constexpr int BM = 128;          // rows of x tile (N dim)
constexpr int BN = 128;          // rows of W tile (O dim)
constexpr int BK = 64;           // K per stage
constexpr int LDK = BK + 8;      // +16B pad: breaks bank aliasing, keeps 16B align
constexpr int NTHREADS = 256;

typedef short bf16x8 __attribute__((ext_vector_type(8)));
typedef float f32x4 __attribute__((ext_vector_type(4)));
typedef float f32x2 __attribute__((ext_vector_type(2)));
typedef __bf16 bf16x2 __attribute__((ext_vector_type(2)));

__device__ __forceinline__ unsigned int cvt_pk_bf16(float a, float b) {
  f32x2 v;
  v[0] = a;
  v[1] = b;
  bf16x2 r = __builtin_convertvector(v, bf16x2);  // v_cvt_pk_bf16_f32 on gfx950
  return __builtin_bit_cast(unsigned int, r);
}

__global__ __launch_bounds__(NTHREADS, 1) void scl_gemm(
    const float* __restrict__ x, const int* __restrict__ subject_id,
    const float* __restrict__ weight, const float* __restrict__ bias,
    float* __restrict__ out) {
  __shared__ __align__(16) unsigned short As[BM * LDK];
  __shared__ __align__(16) unsigned short Bs[BN * LDK];

  const int tid = threadIdx.x;
  const int b = blockIdx.z;
  const int n0 = blockIdx.x * BM;
  const int o0 = blockIdx.y * BN;
  const int sid = subject_id[b];

  const int lane = tid & 63;
  const int wid = tid >> 6;
  const int wm0 = (wid >> 1) * 64;  // wave row offset in tile (N dim)
  const int wn0 = (wid & 1) * 64;   // wave col offset in tile (O dim)
  const int lcol = lane & 15;
  const int lq = lane >> 4;         // 0..3

  // Staging map: 256 threads cover 16 rows x 16 float4-cols per pass, 8 passes.
  const int srow = tid >> 4;        // 0..15
  const int sc4 = (tid & 15) * 4;   // float column 0,4,..,60

  const float* xp = x + (size_t)(b * N_DIM + n0 + srow) * H_DIM + sc4;
  const float* wp = weight + (size_t)(sid * O_DIM + o0 + srow) * H_DIM + sc4;

  f32x4 acc[4][4];
#pragma unroll
  for (int mi = 0; mi < 4; ++mi)
#pragma unroll
    for (int ni = 0; ni < 4; ++ni) {
      f32x4 z = {0.f, 0.f, 0.f, 0.f};
      acc[mi][ni] = z;
    }

  for (int k0 = 0; k0 < H_DIM; k0 += BK) {
    __syncthreads();  // previous compute done before LDS overwrite
#pragma unroll
    for (int i = 0; i < 8; ++i) {
      const int r = srow + i * 16;
      const f32x4 va = *(const f32x4*)(xp + (size_t)(i * 16) * H_DIM + k0);
      const f32x4 vb = *(const f32x4*)(wp + (size_t)(i * 16) * H_DIM + k0);
      uint2 ua, ub;
      ua.x = cvt_pk_bf16(va[0], va[1]);
      ua.y = cvt_pk_bf16(va[2], va[3]);
      ub.x = cvt_pk_bf16(vb[0], vb[1]);
      ub.y = cvt_pk_bf16(vb[2], vb[3]);
      *(uint2*)(&As[r * LDK + sc4]) = ua;  // ds_write_b64, conflict-free
      *(uint2*)(&Bs[r * LDK + sc4]) = ub;
    }
    __syncthreads();

#pragma unroll
    for (int kk = 0; kk < BK; kk += 32) {
      const int kb = kk + lq * 8;  // A/B frag: lane holds 8 contiguous k at quad*8
      bf16x8 af[4], bfr[4];
#pragma unroll
      for (int mi = 0; mi < 4; ++mi)
        af[mi] = *(const bf16x8*)(&As[(wm0 + mi * 16 + lcol) * LDK + kb]);
#pragma unroll
      for (int ni = 0; ni < 4; ++ni)
        bfr[ni] = *(const bf16x8*)(&Bs[(wn0 + ni * 16 + lcol) * LDK + kb]);
#pragma unroll
      for (int mi = 0; mi < 4; ++mi)
#pragma unroll
        for (int ni = 0; ni < 4; ++ni)
          acc[mi][ni] = __builtin_amdgcn_mfma_f32_16x16x32_bf16(
              af[mi], bfr[ni], acc[mi][ni], 0, 0, 0);
    }
  }

  // Epilogue: C/D layout col = lane&15, row = (lane>>4)*4 + reg.
  float bv[4];
#pragma unroll
  for (int ni = 0; ni < 4; ++ni)
    bv[ni] = bias[sid * O_DIM + o0 + wn0 + ni * 16 + lcol];

  float* outb = out + (size_t)(b * N_DIM + n0 + wm0) * O_DIM + o0 + wn0 + lcol;
#pragma unroll
  for (int mi = 0; mi < 4; ++mi) {
#pragma unroll
    for (int r = 0; r < 4; ++r) {
      float* orow = outb + (size_t)(mi * 16 + lq * 4 + r) * O_DIM;
#pragma unroll
      for (int ni = 0; ni < 4; ++ni)
        orow[ni * 16] = acc[mi][ni][r] + bv[ni];
    }
  }
}

extern "C" void kernel_launch(void* const* d_in, const int* in_sizes, int n_in,
                              void* d_out, int out_size, void* d_ws, size_t ws_size,
                              hipStream_t stream) {
  const float* x = (const float*)d_in[0];
  const int* subject_id = (const int*)d_in[1];
  const float* weight = (const float*)d_in[2];
  const float* bias = (const float*)d_in[3];
  float* out = (float*)d_out;

  dim3 grid(N_DIM / BM, O_DIM / BN, B_DIM);  // (4, 8, 32) = 1024 blocks
  scl_gemm<<<grid, NTHREADS, 0, stream>>>(x, subject_id, weight, bias, out);
}

// Round 2
// 188.752 us; speedup vs baseline: 1.1047x; 1.1047x over previous
//
#include <hip/hip_runtime.h>

// SubjectConditionalLinear: y[b,n,o] = sum_h x[b,n,h] * W[sid[b],o,h] + bias[sid[b],o]
// x: [32,512,1024] f32, subject_id: [32] i32, weight: [8,1024,1024] f32, bias: [8,1024] f32
// out: [32,512,1024] f32
//
// R2: two-phase. (1) fp32->bf16 convert of x + all weights into d_ws (pure BW).
// (2) m97-structure GEMM: unpadded 128x64 bf16 LDS tiles staged with
// global_load_lds dwordx4 (no VGPR round-trip, no cvt in loop), 16x16x32 MFMA.

constexpr int S_DIM = 8;
constexpr int O_DIM = 1024;
constexpr int H_DIM = 1024;
constexpr int B_DIM = 32;
constexpr int N_DIM = 512;

constexpr int BM = 128;
constexpr int BN = 128;
constexpr int BK = 64;
constexpr int NTHREADS = 256;

constexpr long long X_ELEMS = (long long)B_DIM * N_DIM * H_DIM;   // 16,777,216
constexpr long long W_ELEMS = (long long)S_DIM * O_DIM * H_DIM;   //  8,388,608
constexpr size_t XB_BYTES = (size_t)X_ELEMS * 2;                  // 32 MiB

typedef short bf16x8 __attribute__((ext_vector_type(8)));
typedef float f32x4 __attribute__((ext_vector_type(4)));
typedef float f32x2 __attribute__((ext_vector_type(2)));
typedef __bf16 bf16x2 __attribute__((ext_vector_type(2)));

__device__ __forceinline__ unsigned int cvt_pk_bf16(float a, float b) {
  f32x2 v;
  v[0] = a;
  v[1] = b;
  bf16x2 r = __builtin_convertvector(v, bf16x2);  // v_cvt_pk_bf16_f32
  return __builtin_bit_cast(unsigned int, r);
}

__device__ __forceinline__ void gload_lds16(const void* g, void* l) {
  __builtin_amdgcn_global_load_lds(
      (const __attribute__((address_space(1))) unsigned int*)g,
      (__attribute__((address_space(3))) unsigned int*)l, 16, 0, 0);
}

// ---------- Phase 1: fp32 -> bf16 convert (x and all 8 weight matrices) ----
__global__ __launch_bounds__(256) void cvt_kernel(
    const float* __restrict__ x, const float* __restrict__ w,
    unsigned short* __restrict__ xb, unsigned short* __restrict__ wb) {
  const long long t = (long long)blockIdx.x * 256 + threadIdx.x;
  const long long XT = X_ELEMS / 8;  // threads covering x, 8 floats each
  const float* src;
  unsigned short* dst;
  long long i;
  if (t < XT) {
    src = x; dst = xb; i = t;
  } else {
    src = w; dst = wb; i = t - XT;
  }
  const f32x4* p = (const f32x4*)(src + i * 8);
  const f32x4 a = p[0];
  const f32x4 c = p[1];
  uint4 u;
  u.x = cvt_pk_bf16(a[0], a[1]);
  u.y = cvt_pk_bf16(a[2], a[3]);
  u.z = cvt_pk_bf16(c[0], c[1]);
  u.w = cvt_pk_bf16(c[2], c[3]);
  *(uint4*)(dst + i * 8) = u;  // 16B store
}

// ---------- Phase 2: bf16 MFMA GEMM, m97 structure -------------------------
__global__ __launch_bounds__(NTHREADS, 4) void scl_gemm(
    const unsigned short* __restrict__ xb, const int* __restrict__ subject_id,
    const unsigned short* __restrict__ wb, const float* __restrict__ bias,
    float* __restrict__ out) {
  __shared__ __align__(16) unsigned short As[BM * BK];  // 16 KiB, unpadded
  __shared__ __align__(16) unsigned short Bs[BN * BK];  // 16 KiB, unpadded

  const int tid = threadIdx.x;
  const int b = blockIdx.z;
  const int n0 = blockIdx.x * BM;
  const int o0 = blockIdx.y * BN;
  const int sid = subject_id[b];

  const int lane = tid & 63;
  const int wid = tid >> 6;
  const int wm0 = (wid >> 1) * 64;
  const int wn0 = (wid & 1) * 64;
  const int lcol = lane & 15;
  const int lq = lane >> 4;

  // Staging: wave w covers rows w*32..w*32+32 of each tile, 4 insts of 8 rows.
  // Lane scatter per inst: row = lane>>3, k-chunk = lane&7 (8 bf16 = 16 B).
  const int srow = wid * 32 + (lane >> 3);
  const int skc = (lane & 7) * 8;
  const unsigned short* ag = xb + (size_t)(b * N_DIM + n0 + srow) * H_DIM + skc;
  const unsigned short* bg = wb + (size_t)(sid * O_DIM + o0 + srow) * H_DIM + skc;
  unsigned short* as_base = &As[(wid * 32) * BK];
  unsigned short* bs_base = &Bs[(wid * 32) * BK];

  f32x4 acc[4][4];
#pragma unroll
  for (int mi = 0; mi < 4; ++mi)
#pragma unroll
    for (int ni = 0; ni < 4; ++ni) {
      f32x4 z = {0.f, 0.f, 0.f, 0.f};
      acc[mi][ni] = z;
    }

  for (int k0 = 0; k0 < H_DIM; k0 += BK) {
    __syncthreads();  // prior compute's ds_reads done before overwrite
#pragma unroll
    for (int i = 0; i < 4; ++i) {
      gload_lds16(ag + (size_t)(i * 8) * H_DIM + k0, as_base + i * 8 * BK);
      gload_lds16(bg + (size_t)(i * 8) * H_DIM + k0, bs_base + i * 8 * BK);
    }
    __syncthreads();  // drains vmcnt: LDS tiles complete

#pragma unroll
    for (int kk = 0; kk < BK; kk += 32) {
      const int kb = kk + lq * 8;
      bf16x8 af[4], bfr[4];
#pragma unroll
      for (int mi = 0; mi < 4; ++mi)
        af[mi] = *(const bf16x8*)(&As[(wm0 + mi * 16 + lcol) * BK + kb]);
#pragma unroll
      for (int ni = 0; ni < 4; ++ni)
        bfr[ni] = *(const bf16x8*)(&Bs[(wn0 + ni * 16 + lcol) * BK + kb]);
#pragma unroll
      for (int mi = 0; mi < 4; ++mi)
#pragma unroll
        for (int ni = 0; ni < 4; ++ni)
          acc[mi][ni] = __builtin_amdgcn_mfma_f32_16x16x32_bf16(
              af[mi], bfr[ni], acc[mi][ni], 0, 0, 0);
    }
  }

  // Epilogue: C/D layout col = lane&15, row = (lane>>4)*4 + reg.
  float bv[4];
#pragma unroll
  for (int ni = 0; ni < 4; ++ni)
    bv[ni] = bias[sid * O_DIM + o0 + wn0 + ni * 16 + lcol];

  float* outb = out + (size_t)(b * N_DIM + n0 + wm0) * O_DIM + o0 + wn0 + lcol;
#pragma unroll
  for (int mi = 0; mi < 4; ++mi) {
#pragma unroll
    for (int r = 0; r < 4; ++r) {
      float* orow = outb + (size_t)(mi * 16 + lq * 4 + r) * O_DIM;
#pragma unroll
      for (int ni = 0; ni < 4; ++ni)
        orow[ni * 16] = acc[mi][ni][r] + bv[ni];
    }
  }
}

extern "C" void kernel_launch(void* const* d_in, const int* in_sizes, int n_in,
                              void* d_out, int out_size, void* d_ws, size_t ws_size,
                              hipStream_t stream) {
  const float* x = (const float*)d_in[0];
  const int* subject_id = (const int*)d_in[1];
  const float* weight = (const float*)d_in[2];
  const float* bias = (const float*)d_in[3];
  float* out = (float*)d_out;

  unsigned short* xb = (unsigned short*)d_ws;                       // 32 MiB
  unsigned short* wb = (unsigned short*)((char*)d_ws + XB_BYTES);   // 16 MiB

  const long long cvt_threads = (X_ELEMS + W_ELEMS) / 8;  // 3,145,728
  cvt_kernel<<<(int)(cvt_threads / 256), 256, 0, stream>>>(x, weight, xb, wb);

  dim3 grid(N_DIM / BM, O_DIM / BN, B_DIM);  // (4, 8, 32) = 1024 blocks
  scl_gemm<<<grid, NTHREADS, 0, stream>>>(xb, subject_id, wb, bias, out);
}